// Round 7
// baseline (206.408 us; speedup 1.0000x reference)
//
#include <hip/hip_runtime.h>
#include <hip/hip_bf16.h>

using bf16x8 = __attribute__((ext_vector_type(8))) short;
using bf16x4 = __attribute__((ext_vector_type(4))) short;
using f32x4  = __attribute__((ext_vector_type(4))) float;

static __device__ __forceinline__ float bf2f(short s) {
  union { unsigned u; float f; } z;
  z.u = ((unsigned)(unsigned short)s) << 16;
  return z.f;
}
static __device__ __forceinline__ short f2bfs(float f) {
  union { __hip_bfloat16 h; short s; } u;
  u.h = __float2bfloat16(f);
  return u.s;
}
static __device__ __forceinline__ float frcp(float x) { return __builtin_amdgcn_rcpf(x); }
static __device__ __forceinline__ float sigm_f(float x) { return frcp(1.f + __expf(-x)); }
static __device__ __forceinline__ float tanh_f(float x) {
  float e = __expf(-2.f * fabsf(x));
  float t = (1.f - e) * frcp(1.f + e);
  return copysignf(t, x);
}

typedef const __attribute__((address_space(1))) unsigned int* gas_u32;
typedef __attribute__((address_space(3))) unsigned int* las_u32;
#define GLOAD16(gp, lp) __builtin_amdgcn_global_load_lds( \
    (gas_u32)(const void*)(gp), (las_u32)(void*)(lp), 16, 0, 0)

// ---------------------------------------------------------------------------
// K1: cheb [3][1024][1024] f32  ->  chebT bf16 [n][k*1024+m]
// ---------------------------------------------------------------------------
__global__ void __launch_bounds__(256) k_transpose_cheb(
    const float* __restrict__ cheb, __hip_bfloat16* __restrict__ chebT) {
  __shared__ float tile[64][65];
  int blk = blockIdx.x;
  int k = blk >> 8;
  int rem = blk & 255;
  int m0 = (rem >> 4) << 6;
  int n0 = (rem & 15) << 6;
  int tx = threadIdx.x & 63;
  int ty = threadIdx.x >> 6;
  const float* src = cheb + (size_t)k * 1024 * 1024;
  #pragma unroll
  for (int i = 0; i < 16; i++) {
    int ml = ty + i * 4;
    tile[ml][tx] = src[(size_t)(m0 + ml) * 1024 + n0 + tx];
  }
  __syncthreads();
  #pragma unroll
  for (int i = 0; i < 16; i++) {
    int nl = ty + i * 4;
    chebT[(size_t)(n0 + nl) * 3072 + k * 1024 + m0 + tx] =
        __float2bfloat16(tile[tx][nl]);
  }
}

// ---------------------------------------------------------------------------
// K2: fused TCN1 (1->64, gated) + w_cheb projection (64 -> 3*16) via MFMA.
// ---------------------------------------------------------------------------
__global__ void __launch_bounds__(256) k_tcn1_proj(
    const float* __restrict__ x,
    const float* __restrict__ w1, const float* __restrict__ b1,
    const float* __restrict__ w2, const float* __restrict__ b2,
    const float* __restrict__ w3, const float* __restrict__ b3,
    const float* __restrict__ wcheb,
    __hip_bfloat16* __restrict__ hwt, int bt0) {
  __shared__ __align__(16) char hls[32768];   // [256 rows][128 B] swizzled
  const int tid = threadIdx.x;
  const int lane = tid & 63, w = tid >> 6;
  const int r16 = lane & 15, kb = lane >> 4;
  const int btl = blockIdx.x >> 2;
  const int m0 = (blockIdx.x & 3) << 8;
  const int bt = bt0 + btl;
  const int b = bt / 22, t = bt % 22;

  const float* xp = x + (size_t)(b * 24 + t) * 1024 + m0 + tid;
  const float x0 = xp[0], x1 = xp[1024], x2 = xp[2048];

  // B fragments: col o = r16, k-elem c = ks*32 + kb*8 + jj; wcheb[k][c][o]
  bf16x8 bw[3][2];
  #pragma unroll
  for (int kk = 0; kk < 3; kk++)
    #pragma unroll
    for (int ks = 0; ks < 2; ks++)
      #pragma unroll
      for (int jj = 0; jj < 8; jj++)
        bw[kk][ks][jj] = f2bfs(wcheb[kk * 1024 + (ks * 32 + kb * 8 + jj) * 16 + r16]);

  // Phase 1: gated conv, 8 channels per chunk -> swizzled LDS
  const int rswz = (tid & 7) << 4;
  #pragma unroll
  for (int cg = 0; cg < 8; cg++) {
    bf16x8 hv;
    #pragma unroll
    for (int j = 0; j < 8; j++) {
      const int c = cg * 8 + j;
      float p  = fmaf(x2, w1[c*3+2], fmaf(x1, w1[c*3+1], fmaf(x0, w1[c*3+0], b1[c])));
      float qz = fmaf(x2, w2[c*3+2], fmaf(x1, w2[c*3+1], fmaf(x0, w2[c*3+0], b2[c])));
      float rz = fmaf(x2, w3[c*3+2], fmaf(x1, w3[c*3+1], fmaf(x0, w3[c*3+0], b3[c])));
      hv[j] = f2bfs(fmaf(p, sigm_f(qz), tanh_f(rz)));
    }
    *(bf16x8*)(hls + tid * 128 + ((cg << 4) ^ rswz)) = hv;
  }
  __syncthreads();

  // Phase 2: projection MFMA. Wave w owns rows [w*64, w*64+64).
  const char* Ab = hls + (w * 64 + r16) * 128;
  const int axor = (r16 & 7) << 4;
  f32x4 acc[4][3];
  #pragma unroll
  for (int mt = 0; mt < 4; mt++)
    #pragma unroll
    for (int kk = 0; kk < 3; kk++) acc[mt][kk] = (f32x4){0.f, 0.f, 0.f, 0.f};

  #pragma unroll
  for (int ks = 0; ks < 2; ks++) {
    #pragma unroll
    for (int mt = 0; mt < 4; mt++) {
      bf16x8 a = *(const bf16x8*)(Ab + mt * 2048 + ((((ks << 2) + kb) << 4) ^ axor));
      #pragma unroll
      for (int kk = 0; kk < 3; kk++)
        acc[mt][kk] = __builtin_amdgcn_mfma_f32_16x16x32_bf16(a, bw[kk][ks], acc[mt][kk], 0, 0, 0);
    }
  }

  __hip_bfloat16* hp = hwt + (size_t)btl * 49152 + r16 * 3072 + m0 + w * 64;
  #pragma unroll
  for (int kk = 0; kk < 3; kk++)
    #pragma unroll
    for (int mt = 0; mt < 4; mt++) {
      bf16x4 v;
      #pragma unroll
      for (int r = 0; r < 4; r++) v[r] = f2bfs(acc[mt][kk][r]);
      *(bf16x4*)(hp + kk * 1024 + mt * 16 + kb * 4) = v;
    }
}

// ---------------------------------------------------------------------------
// K3: tiled GEMM  S[bt][n][o] = ChebT[n][km] * HWT[bt][o][km] + b_cheb[o]
//     128x128 tile, BK=128 (256B LDS rows), single-buffered 64KB LDS,
//     24 K-iterations (half the barrier drains of BK=64), 4 waves,
//     XCD-partitioned grid. Staging: linear dest (i*256+tid)*16, source
//     slot (tid&15)^((tid>>4)&7) inverse-swizzle; reader XOR (r16&7)<<4.
// ---------------------------------------------------------------------------
__global__ void __launch_bounds__(256, 2) k_gemm(
    const __hip_bfloat16* __restrict__ chebT,
    const __hip_bfloat16* __restrict__ hwt,
    const float* __restrict__ b_cheb,
    __hip_bfloat16* __restrict__ sbuf,
    int bt_base) {
  __shared__ __align__(16) char smem[65536];   // A[128][256B] | B[128][256B]
  const int tid = threadIdx.x;
  const int lane = tid & 63;
  const int w = tid >> 6;

  int nt, ct;
  if (gridDim.x == 704) {
    const int xcd = blockIdx.x & 7;      // HW round-robins blockIdx across XCDs
    const int idx = blockIdx.x >> 3;     // 0..87 within this XCD
    nt = ((xcd >> 2) << 2) + (idx & 3);  // nt-group {0..3} or {4..7}
    ct = (xcd & 3) * 22 + (idx >> 2);    // ct-group of 22
  } else {
    nt = blockIdx.x & 7;
    ct = blockIdx.x >> 3;
  }

  // staging: chunk c = i*256 + tid -> row = i*16 + (tid>>4), slot = tid&15
  const int row0 = tid >> 4;                         // 0..15
  const int sswz = ((tid & 15) ^ (row0 & 7)) << 4;   // inverse-swizzled slot
  const char* Ag = (const char*)chebT + (size_t)(nt * 128 + row0) * 6144 + sswz;
  const char* Bg = (const char*)hwt + (size_t)(ct * 8) * 98304 + (size_t)row0 * 6144 + sswz;
  char* Als = smem + tid * 16;
  char* Bls = smem + 32768 + tid * 16;

  const int r16 = lane & 15;
  const int c16 = lane >> 4;
  const int wr = (w >> 1) << 6;
  const int wc = (w & 1) << 6;
  const int axor = (r16 & 7) << 4;
  const char* Abase = smem + (wr + r16) * 256;
  const char* Bbase = smem + 32768 + (wc + r16) * 256;

  f32x4 acc[4][4];
  #pragma unroll
  for (int i = 0; i < 4; i++)
    #pragma unroll
    for (int j = 0; j < 4; j++) acc[i][j] = (f32x4){0.f, 0.f, 0.f, 0.f};

  for (int kt = 0; kt < 24; kt++) {
    __syncthreads();
    const char* a = Ag + kt * 256;
    const char* b = Bg + kt * 256;
    #pragma unroll
    for (int i = 0; i < 8; i++) GLOAD16(a + (size_t)i * 98304, Als + i * 4096);
    #pragma unroll
    for (int i = 0; i < 8; i++) GLOAD16(b + (size_t)i * 98304, Bls + i * 4096);
    __syncthreads();
    #pragma unroll
    for (int ksub = 0; ksub < 4; ksub++) {
      const int ko = (ksub * 64 + c16 * 16) ^ axor;
      bf16x8 af[4], bfr[4];
      #pragma unroll
      for (int i = 0; i < 4; i++) af[i] = *(const bf16x8*)(Abase + i * 4096 + ko);
      #pragma unroll
      for (int j = 0; j < 4; j++) bfr[j] = *(const bf16x8*)(Bbase + j * 4096 + ko);
      #pragma unroll
      for (int i = 0; i < 4; i++)
        #pragma unroll
        for (int j = 0; j < 4; j++)
          acc[i][j] = __builtin_amdgcn_mfma_f32_16x16x32_bf16(af[i], bfr[j], acc[i][j], 0, 0, 0);
    }
  }

  float bias = b_cheb[r16];
  #pragma unroll
  for (int j = 0; j < 4; j++) {
    int gcol = ct * 128 + wc + j * 16 + r16;
    size_t bt_g = (size_t)bt_base + (gcol >> 4);
    int o = gcol & 15;
    #pragma unroll
    for (int i = 0; i < 4; i++) {
      int n0 = nt * 128 + wr + i * 16 + c16 * 4;
      __hip_bfloat16* sp = sbuf + (bt_g * 1024 + n0) * 16 + o;
      #pragma unroll
      for (int r = 0; r < 4; r++)
        sp[r * 16] = __float2bfloat16(acc[i][j][r] + bias);
    }
  }
}

// ---------------------------------------------------------------------------
// K4: fused TCN2 (16->16, gated) via MFMA.
// ---------------------------------------------------------------------------
__global__ void __launch_bounds__(256) k_tcn2(
    const __hip_bfloat16* __restrict__ sbuf,
    const float* __restrict__ w1, const float* __restrict__ b1,
    const float* __restrict__ w2, const float* __restrict__ b2,
    const float* __restrict__ w3, const float* __restrict__ b3,
    float* __restrict__ h2) {
  const int tid = threadIdx.x;
  const int lane = tid & 63, w = tid >> 6;
  const int r16 = lane & 15, kb = lane >> 4;
  const int half = blockIdx.x & 1;
  const int bt2 = blockIdx.x >> 1;
  const int b = bt2 / 20, t2 = bt2 % 20;

  bf16x8 bw[3][2];
  const float* wps[3] = {w1, w2, w3};
  #pragma unroll
  for (int c = 0; c < 3; c++) {
    #pragma unroll
    for (int jj = 0; jj < 8; jj++) {
      int k = kb * 8 + jj;
      bw[c][0][jj] = f2bfs(wps[c][r16 * 48 + (k & 15) * 3 + (k >> 4)]);
      bw[c][1][jj] = (kb < 2) ? f2bfs(wps[c][r16 * 48 + (kb * 8 + jj) * 3 + 2]) : (short)0;
    }
  }
  const float bp = b1[r16], bq = b2[r16], br = b3[r16];

  const char* sb = (const char*)sbuf;
  const size_t slice = (size_t)1024 * 32;
  const int rowbase = half * 512 + w * 128;
  const char* baseA = sb + (size_t)(b * 22 + t2 + (kb >> 1)) * slice
                      + (size_t)(rowbase + r16) * 32 + (kb & 1) * 16;
  const char* baseC = sb + (size_t)(b * 22 + t2 + 2) * slice
                      + (size_t)(rowbase + r16) * 32 + (kb & 1) * 16;
  float* outp = h2 + ((size_t)bt2 * 1024 + rowbase + kb * 4) * 16 + r16;

  const f32x4 zro = {0.f, 0.f, 0.f, 0.f};
  #pragma unroll 2
  for (int i = 0; i < 8; i++) {
    bf16x8 a0 = *(const bf16x8*)(baseA + i * 512);
    bf16x8 a1{};
    if (kb < 2) a1 = *(const bf16x8*)(baseC + i * 512);
    f32x4 ap = __builtin_amdgcn_mfma_f32_16x16x32_bf16(a0, bw[0][0], zro, 0, 0, 0);
    f32x4 aq = __builtin_amdgcn_mfma_f32_16x16x32_bf16(a0, bw[1][0], zro, 0, 0, 0);
    f32x4 ar = __builtin_amdgcn_mfma_f32_16x16x32_bf16(a0, bw[2][0], zro, 0, 0, 0);
    ap = __builtin_amdgcn_mfma_f32_16x16x32_bf16(a1, bw[0][1], ap, 0, 0, 0);
    aq = __builtin_amdgcn_mfma_f32_16x16x32_bf16(a1, bw[1][1], aq, 0, 0, 0);
    ar = __builtin_amdgcn_mfma_f32_16x16x32_bf16(a1, bw[2][1], ar, 0, 0, 0);
    #pragma unroll
    for (int r = 0; r < 4; r++) {
      float h = fmaf(ap[r] + bp, sigm_f(aq[r] + bq), tanh_f(ar[r] + br));
      outp[(size_t)(i * 16 + r) * 16] = h;
    }
  }
}

// ---------------------------------------------------------------------------
// K5: per-node batch stats -> a[n], c[n]
// ---------------------------------------------------------------------------
__global__ void __launch_bounds__(256) k_stats(
    const float* __restrict__ h2, const float* __restrict__ gamma,
    const float* __restrict__ beta, float* __restrict__ ab) {
  int n = blockIdx.x;
  int tid = threadIdx.x;
  float s = 0.f, s2 = 0.f;
  int part = tid & 3;
  for (int bt2 = tid >> 2; bt2 < 640; bt2 += 64) {
    float4 v = *reinterpret_cast<const float4*>(h2 + ((size_t)bt2 * 1024 + n) * 16 + part * 4);
    s  += v.x + v.y + v.z + v.w;
    s2 += v.x*v.x + v.y*v.y + v.z*v.z + v.w*v.w;
  }
  #pragma unroll
  for (int off = 32; off; off >>= 1) { s += __shfl_down(s, off); s2 += __shfl_down(s2, off); }
  __shared__ float rs[4], rs2[4];
  if ((tid & 63) == 0) { rs[tid >> 6] = s; rs2[tid >> 6] = s2; }
  __syncthreads();
  if (tid == 0) {
    float S = rs[0] + rs[1] + rs[2] + rs[3];
    float S2 = rs2[0] + rs2[1] + rs2[2] + rs2[3];
    float mean = S * (1.f / 10240.f);
    float var = S2 * (1.f / 10240.f) - mean * mean;
    float a = gamma[n] * rsqrtf(var + 1e-5f);
    ab[n] = a;
    ab[1024 + n] = beta[n] - mean * a;
  }
}

// ---------------------------------------------------------------------------
// K6: in-place BN + ReLU on d_out
// ---------------------------------------------------------------------------
__global__ void __launch_bounds__(256) k_bnrelu(
    float* __restrict__ h2, const float* __restrict__ ab) {
  size_t i = (size_t)blockIdx.x * 256 + threadIdx.x;
  int n = (int)((i >> 2) & 1023);
  float a = ab[n], c = ab[1024 + n];
  float4* p = reinterpret_cast<float4*>(h2) + i;
  float4 v = *p;
  v.x = fmaxf(0.f, fmaf(v.x, a, c));
  v.y = fmaxf(0.f, fmaf(v.y, a, c));
  v.z = fmaxf(0.f, fmaf(v.z, a, c));
  v.w = fmaxf(0.f, fmaf(v.w, a, c));
  *p = v;
}

// ---------------------------------------------------------------------------
extern "C" void kernel_launch(void* const* d_in, const int* in_sizes, int n_in,
                              void* d_out, int out_size, void* d_ws, size_t ws_size,
                              hipStream_t stream) {
  const float* x     = (const float*)d_in[0];
  const float* cheb  = (const float*)d_in[1];
  const float* t1w1  = (const float*)d_in[2];
  const float* t1b1  = (const float*)d_in[3];
  const float* t1w2  = (const float*)d_in[4];
  const float* t1b2  = (const float*)d_in[5];
  const float* t1w3  = (const float*)d_in[6];
  const float* t1b3  = (const float*)d_in[7];
  const float* wch   = (const float*)d_in[8];
  const float* bch   = (const float*)d_in[9];
  const float* t2w1  = (const float*)d_in[10];
  const float* t2b1  = (const float*)d_in[11];
  const float* t2w2  = (const float*)d_in[12];
  const float* t2b2  = (const float*)d_in[13];
  const float* t2w3  = (const float*)d_in[14];
  const float* t2b3  = (const float*)d_in[15];
  const float* gam   = (const float*)d_in[16];
  const float* bet   = (const float*)d_in[17];

  char* ws = (char*)d_ws;
  __hip_bfloat16* chebT = (__hip_bfloat16*)ws;                   // 6,291,456 B
  __hip_bfloat16* sbuf  = (__hip_bfloat16*)(ws + 6291456);       // 23,068,672 B
  float*          ab    = (float*)(ws + 29360128);               // 8,192 B
  __hip_bfloat16* hwt   = (__hip_bfloat16*)(ws + 29368320);      // chunk buffer

  size_t avail = ws_size > 29368320 ? ws_size - 29368320 : 0;
  int maxch = (int)(avail / 98304);
  maxch &= ~7;
  if (maxch > 704) maxch = 704;
  if (maxch < 8) maxch = 8;

  k_transpose_cheb<<<768, 256, 0, stream>>>(cheb, chebT);

  for (int bt0 = 0; bt0 < 704; bt0 += maxch) {
    int ch = (704 - bt0 < maxch) ? (704 - bt0) : maxch;
    k_tcn1_proj<<<ch * 4, 256, 0, stream>>>(x, t1w1, t1b1, t1w2, t1b2, t1w3, t1b3,
                                            wch, hwt, bt0);
    k_gemm<<<ch, 256, 0, stream>>>(chebT, hwt, bch, sbuf, bt0);
  }

  k_tcn2<<<1280, 256, 0, stream>>>(sbuf, t2w1, t2b1, t2w2, t2b2, t2w3, t2b3,
                                   (float*)d_out);
  k_stats<<<1024, 256, 0, stream>>>((const float*)d_out, gam, bet, ab);
  k_bnrelu<<<10240, 256, 0, stream>>>((float*)d_out, ab);
}

// Round 8
// 182.531 us; speedup vs baseline: 1.1308x; 1.1308x over previous
//
#include <hip/hip_runtime.h>
#include <hip/hip_bf16.h>

using bf16x8 = __attribute__((ext_vector_type(8))) short;
using bf16x4 = __attribute__((ext_vector_type(4))) short;
using f32x4  = __attribute__((ext_vector_type(4))) float;

static __device__ __forceinline__ float bf2f(short s) {
  union { unsigned u; float f; } z;
  z.u = ((unsigned)(unsigned short)s) << 16;
  return z.f;
}
static __device__ __forceinline__ short f2bfs(float f) {
  union { __hip_bfloat16 h; short s; } u;
  u.h = __float2bfloat16(f);
  return u.s;
}
static __device__ __forceinline__ float frcp(float x) { return __builtin_amdgcn_rcpf(x); }
static __device__ __forceinline__ float sigm_f(float x) { return frcp(1.f + __expf(-x)); }
static __device__ __forceinline__ float tanh_f(float x) {
  float e = __expf(-2.f * fabsf(x));
  float t = (1.f - e) * frcp(1.f + e);
  return copysignf(t, x);
}

typedef const __attribute__((address_space(1))) unsigned int* gas_u32;
typedef __attribute__((address_space(3))) unsigned int* las_u32;
#define GLOAD16(gp, lp) __builtin_amdgcn_global_load_lds( \
    (gas_u32)(const void*)(gp), (las_u32)(void*)(lp), 16, 0, 0)

// ---------------------------------------------------------------------------
// K1: cheb [3][1024][1024] f32  ->  chebT bf16 [n][k*1024+m]
// ---------------------------------------------------------------------------
__global__ void __launch_bounds__(256) k_transpose_cheb(
    const float* __restrict__ cheb, __hip_bfloat16* __restrict__ chebT) {
  __shared__ float tile[64][65];
  int blk = blockIdx.x;
  int k = blk >> 8;
  int rem = blk & 255;
  int m0 = (rem >> 4) << 6;
  int n0 = (rem & 15) << 6;
  int tx = threadIdx.x & 63;
  int ty = threadIdx.x >> 6;
  const float* src = cheb + (size_t)k * 1024 * 1024;
  #pragma unroll
  for (int i = 0; i < 16; i++) {
    int ml = ty + i * 4;
    tile[ml][tx] = src[(size_t)(m0 + ml) * 1024 + n0 + tx];
  }
  __syncthreads();
  #pragma unroll
  for (int i = 0; i < 16; i++) {
    int nl = ty + i * 4;
    chebT[(size_t)(n0 + nl) * 3072 + k * 1024 + m0 + tx] =
        __float2bfloat16(tile[tx][nl]);
  }
}

// ---------------------------------------------------------------------------
// K2: fused TCN1 (1->64, gated) + w_cheb projection (64 -> 3*16) via MFMA.
// ---------------------------------------------------------------------------
__global__ void __launch_bounds__(256) k_tcn1_proj(
    const float* __restrict__ x,
    const float* __restrict__ w1, const float* __restrict__ b1,
    const float* __restrict__ w2, const float* __restrict__ b2,
    const float* __restrict__ w3, const float* __restrict__ b3,
    const float* __restrict__ wcheb,
    __hip_bfloat16* __restrict__ hwt, int bt0) {
  __shared__ __align__(16) char hls[32768];   // [256 rows][128 B] swizzled
  const int tid = threadIdx.x;
  const int lane = tid & 63, w = tid >> 6;
  const int r16 = lane & 15, kb = lane >> 4;
  const int btl = blockIdx.x >> 2;
  const int m0 = (blockIdx.x & 3) << 8;
  const int bt = bt0 + btl;
  const int b = bt / 22, t = bt % 22;

  const float* xp = x + (size_t)(b * 24 + t) * 1024 + m0 + tid;
  const float x0 = xp[0], x1 = xp[1024], x2 = xp[2048];

  // B fragments: col o = r16, k-elem c = ks*32 + kb*8 + jj; wcheb[k][c][o]
  bf16x8 bw[3][2];
  #pragma unroll
  for (int kk = 0; kk < 3; kk++)
    #pragma unroll
    for (int ks = 0; ks < 2; ks++)
      #pragma unroll
      for (int jj = 0; jj < 8; jj++)
        bw[kk][ks][jj] = f2bfs(wcheb[kk * 1024 + (ks * 32 + kb * 8 + jj) * 16 + r16]);

  // Phase 1: gated conv, 8 channels per chunk -> swizzled LDS
  const int rswz = (tid & 7) << 4;
  #pragma unroll
  for (int cg = 0; cg < 8; cg++) {
    bf16x8 hv;
    #pragma unroll
    for (int j = 0; j < 8; j++) {
      const int c = cg * 8 + j;
      float p  = fmaf(x2, w1[c*3+2], fmaf(x1, w1[c*3+1], fmaf(x0, w1[c*3+0], b1[c])));
      float qz = fmaf(x2, w2[c*3+2], fmaf(x1, w2[c*3+1], fmaf(x0, w2[c*3+0], b2[c])));
      float rz = fmaf(x2, w3[c*3+2], fmaf(x1, w3[c*3+1], fmaf(x0, w3[c*3+0], b3[c])));
      hv[j] = f2bfs(fmaf(p, sigm_f(qz), tanh_f(rz)));
    }
    *(bf16x8*)(hls + tid * 128 + ((cg << 4) ^ rswz)) = hv;
  }
  __syncthreads();

  // Phase 2: projection MFMA. Wave w owns rows [w*64, w*64+64).
  const char* Ab = hls + (w * 64 + r16) * 128;
  const int axor = (r16 & 7) << 4;
  f32x4 acc[4][3];
  #pragma unroll
  for (int mt = 0; mt < 4; mt++)
    #pragma unroll
    for (int kk = 0; kk < 3; kk++) acc[mt][kk] = (f32x4){0.f, 0.f, 0.f, 0.f};

  #pragma unroll
  for (int ks = 0; ks < 2; ks++) {
    #pragma unroll
    for (int mt = 0; mt < 4; mt++) {
      bf16x8 a = *(const bf16x8*)(Ab + mt * 2048 + ((((ks << 2) + kb) << 4) ^ axor));
      #pragma unroll
      for (int kk = 0; kk < 3; kk++)
        acc[mt][kk] = __builtin_amdgcn_mfma_f32_16x16x32_bf16(a, bw[kk][ks], acc[mt][kk], 0, 0, 0);
    }
  }

  __hip_bfloat16* hp = hwt + (size_t)btl * 49152 + r16 * 3072 + m0 + w * 64;
  #pragma unroll
  for (int kk = 0; kk < 3; kk++)
    #pragma unroll
    for (int mt = 0; mt < 4; mt++) {
      bf16x4 v;
      #pragma unroll
      for (int r = 0; r < 4; r++) v[r] = f2bfs(acc[mt][kk][r]);
      *(bf16x4*)(hp + kk * 1024 + mt * 16 + kb * 4) = v;
    }
}

// ---------------------------------------------------------------------------
// K3: tiled GEMM  S[bt][n][o] = ChebT[n][km] * HWT[bt][o][km] + b_cheb[o]
//     EXACT r5 structure (proven 75.7us / 937 TF): 128x128 tile, BK=64,
//     single-buffered 32KB LDS, 2-barrier K-loop, XCD-partitioned grid.
// ---------------------------------------------------------------------------
__global__ void __launch_bounds__(256, 2) k_gemm(
    const __hip_bfloat16* __restrict__ chebT,
    const __hip_bfloat16* __restrict__ hwt,
    const float* __restrict__ b_cheb,
    __hip_bfloat16* __restrict__ sbuf,
    int bt_base) {
  __shared__ __align__(16) char smem[32768];
  const int tid = threadIdx.x;
  const int lane = tid & 63;
  const int w = tid >> 6;

  int nt, ct;
  if (gridDim.x == 704) {
    const int xcd = blockIdx.x & 7;      // HW round-robins blockIdx across XCDs
    const int idx = blockIdx.x >> 3;     // 0..87 within this XCD
    nt = ((xcd >> 2) << 2) + (idx & 3);  // nt-group {0..3} or {4..7}
    ct = (xcd & 3) * 22 + (idx >> 2);    // ct-group of 22
  } else {
    nt = blockIdx.x & 7;
    ct = blockIdx.x >> 3;
  }

  const int srow = tid >> 3;
  const int sswz = ((tid & 7) ^ (srow & 7)) << 4;
  const char* Ag = (const char*)chebT + (size_t)(nt * 128 + srow) * 6144 + sswz;
  const int btl = srow >> 4, so = srow & 15;
  const char* Bg = (const char*)hwt + (size_t)(ct * 8 + btl) * 98304 + (size_t)so * 6144 + sswz;
  char* Als = smem + w * 1024;
  char* Bls = smem + 16384 + w * 1024;

  const int r16 = lane & 15;
  const int c16 = lane >> 4;
  const int wr = (w >> 1) << 6;
  const int wc = (w & 1) << 6;
  const int axor = (r16 & 7) << 4;
  const char* Abase = smem + (wr + r16) * 128;
  const char* Bbase = smem + 16384 + (wc + r16) * 128;

  f32x4 acc[4][4];
  #pragma unroll
  for (int i = 0; i < 4; i++)
    #pragma unroll
    for (int j = 0; j < 4; j++) acc[i][j] = (f32x4){0.f, 0.f, 0.f, 0.f};

  for (int kt = 0; kt < 48; kt++) {
    __syncthreads();
    const char* a = Ag + kt * 128;
    const char* b = Bg + kt * 128;
    #pragma unroll
    for (int i = 0; i < 4; i++) GLOAD16(a + i * 196608, Als + i * 4096);
    #pragma unroll
    for (int i = 0; i < 4; i++) GLOAD16(b + i * 196608, Bls + i * 4096);
    __syncthreads();
    #pragma unroll
    for (int ksub = 0; ksub < 2; ksub++) {
      const int ko = (ksub * 64 + c16 * 16) ^ axor;
      bf16x8 af[4], bfr[4];
      #pragma unroll
      for (int i = 0; i < 4; i++) af[i] = *(const bf16x8*)(Abase + i * 2048 + ko);
      #pragma unroll
      for (int j = 0; j < 4; j++) bfr[j] = *(const bf16x8*)(Bbase + j * 2048 + ko);
      #pragma unroll
      for (int i = 0; i < 4; i++)
        #pragma unroll
        for (int j = 0; j < 4; j++)
          acc[i][j] = __builtin_amdgcn_mfma_f32_16x16x32_bf16(af[i], bfr[j], acc[i][j], 0, 0, 0);
    }
  }

  float bias = b_cheb[r16];
  #pragma unroll
  for (int j = 0; j < 4; j++) {
    int gcol = ct * 128 + wc + j * 16 + r16;
    size_t bt_g = (size_t)bt_base + (gcol >> 4);
    int o = gcol & 15;
    #pragma unroll
    for (int i = 0; i < 4; i++) {
      int n0 = nt * 128 + wr + i * 16 + c16 * 4;
      __hip_bfloat16* sp = sbuf + (bt_g * 1024 + n0) * 16 + o;
      #pragma unroll
      for (int r = 0; r < 4; r++)
        sp[r * 16] = __float2bfloat16(acc[i][j][r] + bias);
    }
  }
}

// ---------------------------------------------------------------------------
// K4: fused TCN2 (16->16, gated) via MFMA; output now bf16 to workspace.
// ---------------------------------------------------------------------------
__global__ void __launch_bounds__(256) k_tcn2(
    const __hip_bfloat16* __restrict__ sbuf,
    const float* __restrict__ w1, const float* __restrict__ b1,
    const float* __restrict__ w2, const float* __restrict__ b2,
    const float* __restrict__ w3, const float* __restrict__ b3,
    __hip_bfloat16* __restrict__ h2b) {
  const int tid = threadIdx.x;
  const int lane = tid & 63, w = tid >> 6;
  const int r16 = lane & 15, kb = lane >> 4;
  const int half = blockIdx.x & 1;
  const int bt2 = blockIdx.x >> 1;
  const int b = bt2 / 20, t2 = bt2 % 20;

  bf16x8 bw[3][2];
  const float* wps[3] = {w1, w2, w3};
  #pragma unroll
  for (int c = 0; c < 3; c++) {
    #pragma unroll
    for (int jj = 0; jj < 8; jj++) {
      int k = kb * 8 + jj;
      bw[c][0][jj] = f2bfs(wps[c][r16 * 48 + (k & 15) * 3 + (k >> 4)]);
      bw[c][1][jj] = (kb < 2) ? f2bfs(wps[c][r16 * 48 + (kb * 8 + jj) * 3 + 2]) : (short)0;
    }
  }
  const float bp = b1[r16], bq = b2[r16], br = b3[r16];

  const char* sb = (const char*)sbuf;
  const size_t slice = (size_t)1024 * 32;
  const int rowbase = half * 512 + w * 128;
  const char* baseA = sb + (size_t)(b * 22 + t2 + (kb >> 1)) * slice
                      + (size_t)(rowbase + r16) * 32 + (kb & 1) * 16;
  const char* baseC = sb + (size_t)(b * 22 + t2 + 2) * slice
                      + (size_t)(rowbase + r16) * 32 + (kb & 1) * 16;
  __hip_bfloat16* outp = h2b + ((size_t)bt2 * 1024 + rowbase + kb * 4) * 16 + r16;

  const f32x4 zro = {0.f, 0.f, 0.f, 0.f};
  #pragma unroll 2
  for (int i = 0; i < 8; i++) {
    bf16x8 a0 = *(const bf16x8*)(baseA + i * 512);
    bf16x8 a1{};
    if (kb < 2) a1 = *(const bf16x8*)(baseC + i * 512);
    f32x4 ap = __builtin_amdgcn_mfma_f32_16x16x32_bf16(a0, bw[0][0], zro, 0, 0, 0);
    f32x4 aq = __builtin_amdgcn_mfma_f32_16x16x32_bf16(a0, bw[1][0], zro, 0, 0, 0);
    f32x4 ar = __builtin_amdgcn_mfma_f32_16x16x32_bf16(a0, bw[2][0], zro, 0, 0, 0);
    ap = __builtin_amdgcn_mfma_f32_16x16x32_bf16(a1, bw[0][1], ap, 0, 0, 0);
    aq = __builtin_amdgcn_mfma_f32_16x16x32_bf16(a1, bw[1][1], aq, 0, 0, 0);
    ar = __builtin_amdgcn_mfma_f32_16x16x32_bf16(a1, bw[2][1], ar, 0, 0, 0);
    #pragma unroll
    for (int r = 0; r < 4; r++) {
      float h = fmaf(ap[r] + bp, sigm_f(aq[r] + bq), tanh_f(ar[r] + br));
      outp[(size_t)(i * 16 + r) * 16] = __float2bfloat16(h);
    }
  }
}

// ---------------------------------------------------------------------------
// K5: per-node batch stats from bf16 h2 -> a[n], c[n]
// ---------------------------------------------------------------------------
__global__ void __launch_bounds__(256) k_stats(
    const __hip_bfloat16* __restrict__ h2b, const float* __restrict__ gamma,
    const float* __restrict__ beta, float* __restrict__ ab) {
  int n = blockIdx.x;
  int tid = threadIdx.x;
  float s = 0.f, s2 = 0.f;
  int part = tid & 1;                       // which 16B half of the 32B row
  for (int bt2 = tid >> 1; bt2 < 640; bt2 += 128) {
    bf16x8 v = *(const bf16x8*)((const char*)h2b +
        ((size_t)bt2 * 1024 + n) * 32 + part * 16);
    #pragma unroll
    for (int j = 0; j < 8; j++) { float f = bf2f(v[j]); s += f; s2 += f * f; }
  }
  #pragma unroll
  for (int off = 32; off; off >>= 1) { s += __shfl_down(s, off); s2 += __shfl_down(s2, off); }
  __shared__ float rs[4], rs2[4];
  if ((tid & 63) == 0) { rs[tid >> 6] = s; rs2[tid >> 6] = s2; }
  __syncthreads();
  if (tid == 0) {
    float S = rs[0] + rs[1] + rs[2] + rs[3];
    float S2 = rs2[0] + rs2[1] + rs2[2] + rs2[3];
    float mean = S * (1.f / 10240.f);
    float var = S2 * (1.f / 10240.f) - mean * mean;
    float a = gamma[n] * rsqrtf(var + 1e-5f);
    ab[n] = a;
    ab[1024 + n] = beta[n] - mean * a;
  }
}

// ---------------------------------------------------------------------------
// K6: BN + ReLU: bf16 h2 -> f32 d_out
// ---------------------------------------------------------------------------
__global__ void __launch_bounds__(256) k_bnrelu(
    const __hip_bfloat16* __restrict__ h2b, const float* __restrict__ ab,
    float* __restrict__ out) {
  size_t c = (size_t)blockIdx.x * 256 + threadIdx.x;   // 8-elem chunk id
  int n = (int)((c >> 1) & 1023);
  float a = ab[n], cc = ab[1024 + n];
  bf16x8 v = *(const bf16x8*)((const char*)h2b + c * 16);
  float4* op = reinterpret_cast<float4*>(out + c * 8);
  float4 o0, o1;
  o0.x = fmaxf(0.f, fmaf(bf2f(v[0]), a, cc));
  o0.y = fmaxf(0.f, fmaf(bf2f(v[1]), a, cc));
  o0.z = fmaxf(0.f, fmaf(bf2f(v[2]), a, cc));
  o0.w = fmaxf(0.f, fmaf(bf2f(v[3]), a, cc));
  o1.x = fmaxf(0.f, fmaf(bf2f(v[4]), a, cc));
  o1.y = fmaxf(0.f, fmaf(bf2f(v[5]), a, cc));
  o1.z = fmaxf(0.f, fmaf(bf2f(v[6]), a, cc));
  o1.w = fmaxf(0.f, fmaf(bf2f(v[7]), a, cc));
  op[0] = o0;
  op[1] = o1;
}

// ---------------------------------------------------------------------------
extern "C" void kernel_launch(void* const* d_in, const int* in_sizes, int n_in,
                              void* d_out, int out_size, void* d_ws, size_t ws_size,
                              hipStream_t stream) {
  const float* x     = (const float*)d_in[0];
  const float* cheb  = (const float*)d_in[1];
  const float* t1w1  = (const float*)d_in[2];
  const float* t1b1  = (const float*)d_in[3];
  const float* t1w2  = (const float*)d_in[4];
  const float* t1b2  = (const float*)d_in[5];
  const float* t1w3  = (const float*)d_in[6];
  const float* t1b3  = (const float*)d_in[7];
  const float* wch   = (const float*)d_in[8];
  const float* bch   = (const float*)d_in[9];
  const float* t2w1  = (const float*)d_in[10];
  const float* t2b1  = (const float*)d_in[11];
  const float* t2w2  = (const float*)d_in[12];
  const float* t2b2  = (const float*)d_in[13];
  const float* t2w3  = (const float*)d_in[14];
  const float* t2b3  = (const float*)d_in[15];
  const float* gam   = (const float*)d_in[16];
  const float* bet   = (const float*)d_in[17];

  char* ws = (char*)d_ws;
  __hip_bfloat16* chebT = (__hip_bfloat16*)ws;                   // 6,291,456 B
  __hip_bfloat16* sbuf  = (__hip_bfloat16*)(ws + 6291456);       // 23,068,672 B
  float*          ab    = (float*)(ws + 29360128);               // 8,192 B
  __hip_bfloat16* h2b   = (__hip_bfloat16*)(ws + 29368320);      // 20,971,520 B
  __hip_bfloat16* hwt   = (__hip_bfloat16*)(ws + 50339840);      // chunk buffer

  size_t avail = ws_size > 50339840 ? ws_size - 50339840 : 0;
  int maxch = (int)(avail / 98304);
  maxch &= ~7;
  if (maxch > 704) maxch = 704;
  if (maxch < 8) maxch = 8;

  k_transpose_cheb<<<768, 256, 0, stream>>>(cheb, chebT);

  for (int bt0 = 0; bt0 < 704; bt0 += maxch) {
    int ch = (704 - bt0 < maxch) ? (704 - bt0) : maxch;
    k_tcn1_proj<<<ch * 4, 256, 0, stream>>>(x, t1w1, t1b1, t1w2, t1b2, t1w3, t1b3,
                                            wch, hwt, bt0);
    k_gemm<<<ch, 256, 0, stream>>>(chebT, hwt, bch, sbuf, bt0);
  }

  k_tcn2<<<1280, 256, 0, stream>>>(sbuf, t2w1, t2b1, t2w2, t2b2, t2w3, t2b3, h2b);
  k_stats<<<1024, 256, 0, stream>>>(h2b, gam, bet, ab);
  k_bnrelu<<<5120, 256, 0, stream>>>(h2b, ab, (float*)d_out);
}

// Round 9
// 179.994 us; speedup vs baseline: 1.1467x; 1.0141x over previous
//
#include <hip/hip_runtime.h>
#include <hip/hip_bf16.h>

using bf16x8 = __attribute__((ext_vector_type(8))) short;
using bf16x4 = __attribute__((ext_vector_type(4))) short;
using f32x4  = __attribute__((ext_vector_type(4))) float;
using f32x2  = __attribute__((ext_vector_type(2))) float;

static __device__ __forceinline__ float bf2f(short s) {
  union { unsigned u; float f; } z;
  z.u = ((unsigned)(unsigned short)s) << 16;
  return z.f;
}
static __device__ __forceinline__ short f2bfs(float f) {
  union { __hip_bfloat16 h; short s; } u;
  u.h = __float2bfloat16(f);
  return u.s;
}
static __device__ __forceinline__ float frcp(float x) { return __builtin_amdgcn_rcpf(x); }
static __device__ __forceinline__ float sigm_f(float x) { return frcp(1.f + __expf(-x)); }
static __device__ __forceinline__ float tanh_f(float x) {
  // tanh(x) = 2*sigmoid(2x) - 1 ; inf-safe: x<<0 -> exp(+inf)=inf -> rcp=0 -> -1
  return fmaf(2.f, frcp(1.f + __expf(-2.f * x)), -1.f);
}

typedef const __attribute__((address_space(1))) unsigned int* gas_u32;
typedef __attribute__((address_space(3))) unsigned int* las_u32;
#define GLOAD16(gp, lp) __builtin_amdgcn_global_load_lds( \
    (gas_u32)(const void*)(gp), (las_u32)(void*)(lp), 16, 0, 0)

// ---------------------------------------------------------------------------
// K1: cheb [3][1024][1024] f32 -> chebT bf16 [n][k*1024+m]
//     + 1 extra block (blk==768): pack w_cheb into bf16 B-fragment layout
//       pbw[((kk*2+ks)*64 + lane)*8 + jj] = wcheb[kk][ks*32+(lane>>4)*8+jj][lane&15]
// ---------------------------------------------------------------------------
__global__ void __launch_bounds__(256) k_transpose_cheb(
    const float* __restrict__ cheb, __hip_bfloat16* __restrict__ chebT,
    const float* __restrict__ wcheb, __hip_bfloat16* __restrict__ pbw) {
  int blk = blockIdx.x;
  if (blk == 768) {
    for (int i = threadIdx.x; i < 3072; i += 256) {
      int jj = i & 7, lane = (i >> 3) & 63, ksk = i >> 9;
      int kk = ksk >> 1, ks = ksk & 1;
      int c = ks * 32 + ((lane >> 4) & 3) * 8 + jj;
      int o = lane & 15;
      pbw[i] = __float2bfloat16(wcheb[kk * 1024 + c * 16 + o]);
    }
    return;
  }
  __shared__ float tile[64][65];
  int k = blk >> 8;
  int rem = blk & 255;
  int m0 = (rem >> 4) << 6;
  int n0 = (rem & 15) << 6;
  int tx = threadIdx.x & 63;
  int ty = threadIdx.x >> 6;
  const float* src = cheb + (size_t)k * 1024 * 1024;
  #pragma unroll
  for (int i = 0; i < 16; i++) {
    int ml = ty + i * 4;
    tile[ml][tx] = src[(size_t)(m0 + ml) * 1024 + n0 + tx];
  }
  __syncthreads();
  #pragma unroll
  for (int i = 0; i < 16; i++) {
    int nl = ty + i * 4;
    chebT[(size_t)(n0 + nl) * 3072 + k * 1024 + m0 + tx] =
        __float2bfloat16(tile[tx][nl]);
  }
}

// ---------------------------------------------------------------------------
// K2: fused TCN1 (1->64, gated) + w_cheb projection (64 -> 3*16) via MFMA.
//     Conv phase: packed f32x2 (v_pk_fma_f32), lean sigmoid/tanh.
//     B-fragments: 6 coalesced bf16x8 loads from pre-packed pbw.
// ---------------------------------------------------------------------------
__global__ void __launch_bounds__(256) k_tcn1_proj(
    const float* __restrict__ x,
    const float* __restrict__ w1, const float* __restrict__ b1,
    const float* __restrict__ w2, const float* __restrict__ b2,
    const float* __restrict__ w3, const float* __restrict__ b3,
    const __hip_bfloat16* __restrict__ pbw,
    __hip_bfloat16* __restrict__ hwt, int bt0) {
  __shared__ __align__(16) char hls[32768];   // [256 rows][128 B] swizzled
  const int tid = threadIdx.x;
  const int lane = tid & 63, w = tid >> 6;
  const int r16 = lane & 15, kb = lane >> 4;
  const int btl = blockIdx.x >> 2;
  const int m0 = (blockIdx.x & 3) << 8;
  const int bt = bt0 + btl;
  const int b = bt / 22, t = bt % 22;

  const float* xp = x + (size_t)(b * 24 + t) * 1024 + m0 + tid;
  const float x0 = xp[0], x1 = xp[1024], x2 = xp[2048];
  const f32x2 x0v = {x0, x0}, x1v = {x1, x1}, x2v = {x2, x2};

  // B fragments: coalesced 16B loads from pre-packed layout
  bf16x8 bw[3][2];
  const bf16x8* pb8 = reinterpret_cast<const bf16x8*>(pbw);
  #pragma unroll
  for (int kk = 0; kk < 3; kk++)
    #pragma unroll
    for (int ks = 0; ks < 2; ks++)
      bw[kk][ks] = pb8[(kk * 2 + ks) * 64 + lane];

  // Phase 1: gated conv (channel pairs via packed f32), 8 ch/chunk -> swizzled LDS
  const int rswz = (tid & 7) << 4;
  #pragma unroll
  for (int cg = 0; cg < 8; cg++) {
    bf16x8 hv;
    #pragma unroll
    for (int j2 = 0; j2 < 4; j2++) {
      const int c2 = cg * 4 + j2;           // pair index; channels 2c2, 2c2+1
      const int wi = 6 * c2;
      f32x2 pw, qw, rw;
      pw = (f32x2){b1[2*c2], b1[2*c2+1]};
      qw = (f32x2){b2[2*c2], b2[2*c2+1]};
      rw = (f32x2){b3[2*c2], b3[2*c2+1]};
      pw = __builtin_elementwise_fma(x0v, (f32x2){w1[wi], w1[wi+3]}, pw);
      qw = __builtin_elementwise_fma(x0v, (f32x2){w2[wi], w2[wi+3]}, qw);
      rw = __builtin_elementwise_fma(x0v, (f32x2){w3[wi], w3[wi+3]}, rw);
      pw = __builtin_elementwise_fma(x1v, (f32x2){w1[wi+1], w1[wi+4]}, pw);
      qw = __builtin_elementwise_fma(x1v, (f32x2){w2[wi+1], w2[wi+4]}, qw);
      rw = __builtin_elementwise_fma(x1v, (f32x2){w3[wi+1], w3[wi+4]}, rw);
      pw = __builtin_elementwise_fma(x2v, (f32x2){w1[wi+2], w1[wi+5]}, pw);
      qw = __builtin_elementwise_fma(x2v, (f32x2){w2[wi+2], w2[wi+5]}, qw);
      rw = __builtin_elementwise_fma(x2v, (f32x2){w3[wi+2], w3[wi+5]}, rw);
      hv[j2*2+0] = f2bfs(fmaf(pw.x, sigm_f(qw.x), tanh_f(rw.x)));
      hv[j2*2+1] = f2bfs(fmaf(pw.y, sigm_f(qw.y), tanh_f(rw.y)));
    }
    *(bf16x8*)(hls + tid * 128 + ((cg << 4) ^ rswz)) = hv;
  }
  __syncthreads();

  // Phase 2: projection MFMA. Wave w owns rows [w*64, w*64+64).
  const char* Ab = hls + (w * 64 + r16) * 128;
  const int axor = (r16 & 7) << 4;
  f32x4 acc[4][3];
  #pragma unroll
  for (int mt = 0; mt < 4; mt++)
    #pragma unroll
    for (int kk = 0; kk < 3; kk++) acc[mt][kk] = (f32x4){0.f, 0.f, 0.f, 0.f};

  #pragma unroll
  for (int ks = 0; ks < 2; ks++) {
    #pragma unroll
    for (int mt = 0; mt < 4; mt++) {
      bf16x8 a = *(const bf16x8*)(Ab + mt * 2048 + ((((ks << 2) + kb) << 4) ^ axor));
      #pragma unroll
      for (int kk = 0; kk < 3; kk++)
        acc[mt][kk] = __builtin_amdgcn_mfma_f32_16x16x32_bf16(a, bw[kk][ks], acc[mt][kk], 0, 0, 0);
    }
  }

  __hip_bfloat16* hp = hwt + (size_t)btl * 49152 + r16 * 3072 + m0 + w * 64;
  #pragma unroll
  for (int kk = 0; kk < 3; kk++)
    #pragma unroll
    for (int mt = 0; mt < 4; mt++) {
      bf16x4 v;
      #pragma unroll
      for (int r = 0; r < 4; r++) v[r] = f2bfs(acc[mt][kk][r]);
      *(bf16x4*)(hp + kk * 1024 + mt * 16 + kb * 4) = v;
    }
}

// ---------------------------------------------------------------------------
// K3: tiled GEMM  S[bt][n][o] = ChebT[n][km] * HWT[bt][o][km] + b_cheb[o]
//     EXACT r5 structure (proven 75.5us / 937 TF).
// ---------------------------------------------------------------------------
__global__ void __launch_bounds__(256, 2) k_gemm(
    const __hip_bfloat16* __restrict__ chebT,
    const __hip_bfloat16* __restrict__ hwt,
    const float* __restrict__ b_cheb,
    __hip_bfloat16* __restrict__ sbuf,
    int bt_base) {
  __shared__ __align__(16) char smem[32768];
  const int tid = threadIdx.x;
  const int lane = tid & 63;
  const int w = tid >> 6;

  int nt, ct;
  if (gridDim.x == 704) {
    const int xcd = blockIdx.x & 7;
    const int idx = blockIdx.x >> 3;
    nt = ((xcd >> 2) << 2) + (idx & 3);
    ct = (xcd & 3) * 22 + (idx >> 2);
  } else {
    nt = blockIdx.x & 7;
    ct = blockIdx.x >> 3;
  }

  const int srow = tid >> 3;
  const int sswz = ((tid & 7) ^ (srow & 7)) << 4;
  const char* Ag = (const char*)chebT + (size_t)(nt * 128 + srow) * 6144 + sswz;
  const int btl = srow >> 4, so = srow & 15;
  const char* Bg = (const char*)hwt + (size_t)(ct * 8 + btl) * 98304 + (size_t)so * 6144 + sswz;
  char* Als = smem + w * 1024;
  char* Bls = smem + 16384 + w * 1024;

  const int r16 = lane & 15;
  const int c16 = lane >> 4;
  const int wr = (w >> 1) << 6;
  const int wc = (w & 1) << 6;
  const int axor = (r16 & 7) << 4;
  const char* Abase = smem + (wr + r16) * 128;
  const char* Bbase = smem + 16384 + (wc + r16) * 128;

  f32x4 acc[4][4];
  #pragma unroll
  for (int i = 0; i < 4; i++)
    #pragma unroll
    for (int j = 0; j < 4; j++) acc[i][j] = (f32x4){0.f, 0.f, 0.f, 0.f};

  for (int kt = 0; kt < 48; kt++) {
    __syncthreads();
    const char* a = Ag + kt * 128;
    const char* b = Bg + kt * 128;
    #pragma unroll
    for (int i = 0; i < 4; i++) GLOAD16(a + i * 196608, Als + i * 4096);
    #pragma unroll
    for (int i = 0; i < 4; i++) GLOAD16(b + i * 196608, Bls + i * 4096);
    __syncthreads();
    #pragma unroll
    for (int ksub = 0; ksub < 2; ksub++) {
      const int ko = (ksub * 64 + c16 * 16) ^ axor;
      bf16x8 af[4], bfr[4];
      #pragma unroll
      for (int i = 0; i < 4; i++) af[i] = *(const bf16x8*)(Abase + i * 2048 + ko);
      #pragma unroll
      for (int j = 0; j < 4; j++) bfr[j] = *(const bf16x8*)(Bbase + j * 2048 + ko);
      #pragma unroll
      for (int i = 0; i < 4; i++)
        #pragma unroll
        for (int j = 0; j < 4; j++)
          acc[i][j] = __builtin_amdgcn_mfma_f32_16x16x32_bf16(af[i], bfr[j], acc[i][j], 0, 0, 0);
    }
  }

  float bias = b_cheb[r16];
  #pragma unroll
  for (int j = 0; j < 4; j++) {
    int gcol = ct * 128 + wc + j * 16 + r16;
    size_t bt_g = (size_t)bt_base + (gcol >> 4);
    int o = gcol & 15;
    #pragma unroll
    for (int i = 0; i < 4; i++) {
      int n0 = nt * 128 + wr + i * 16 + c16 * 4;
      __hip_bfloat16* sp = sbuf + (bt_g * 1024 + n0) * 16 + o;
      #pragma unroll
      for (int r = 0; r < 4; r++)
        sp[r * 16] = __float2bfloat16(acc[i][j][r] + bias);
    }
  }
}

// ---------------------------------------------------------------------------
// K4: fused TCN2 (16->16, gated) via MFMA; output bf16 to workspace.
// ---------------------------------------------------------------------------
__global__ void __launch_bounds__(256) k_tcn2(
    const __hip_bfloat16* __restrict__ sbuf,
    const float* __restrict__ w1, const float* __restrict__ b1,
    const float* __restrict__ w2, const float* __restrict__ b2,
    const float* __restrict__ w3, const float* __restrict__ b3,
    __hip_bfloat16* __restrict__ h2b) {
  const int tid = threadIdx.x;
  const int lane = tid & 63, w = tid >> 6;
  const int r16 = lane & 15, kb = lane >> 4;
  const int half = blockIdx.x & 1;
  const int bt2 = blockIdx.x >> 1;
  const int b = bt2 / 20, t2 = bt2 % 20;

  bf16x8 bw[3][2];
  const float* wps[3] = {w1, w2, w3};
  #pragma unroll
  for (int c = 0; c < 3; c++) {
    #pragma unroll
    for (int jj = 0; jj < 8; jj++) {
      int k = kb * 8 + jj;
      bw[c][0][jj] = f2bfs(wps[c][r16 * 48 + (k & 15) * 3 + (k >> 4)]);
      bw[c][1][jj] = (kb < 2) ? f2bfs(wps[c][r16 * 48 + (kb * 8 + jj) * 3 + 2]) : (short)0;
    }
  }
  const float bp = b1[r16], bq = b2[r16], br = b3[r16];

  const char* sb = (const char*)sbuf;
  const size_t slice = (size_t)1024 * 32;
  const int rowbase = half * 512 + w * 128;
  const char* baseA = sb + (size_t)(b * 22 + t2 + (kb >> 1)) * slice
                      + (size_t)(rowbase + r16) * 32 + (kb & 1) * 16;
  const char* baseC = sb + (size_t)(b * 22 + t2 + 2) * slice
                      + (size_t)(rowbase + r16) * 32 + (kb & 1) * 16;
  __hip_bfloat16* outp = h2b + ((size_t)bt2 * 1024 + rowbase + kb * 4) * 16 + r16;

  const f32x4 zro = {0.f, 0.f, 0.f, 0.f};
  #pragma unroll 2
  for (int i = 0; i < 8; i++) {
    bf16x8 a0 = *(const bf16x8*)(baseA + i * 512);
    bf16x8 a1{};
    if (kb < 2) a1 = *(const bf16x8*)(baseC + i * 512);
    f32x4 ap = __builtin_amdgcn_mfma_f32_16x16x32_bf16(a0, bw[0][0], zro, 0, 0, 0);
    f32x4 aq = __builtin_amdgcn_mfma_f32_16x16x32_bf16(a0, bw[1][0], zro, 0, 0, 0);
    f32x4 ar = __builtin_amdgcn_mfma_f32_16x16x32_bf16(a0, bw[2][0], zro, 0, 0, 0);
    ap = __builtin_amdgcn_mfma_f32_16x16x32_bf16(a1, bw[0][1], ap, 0, 0, 0);
    aq = __builtin_amdgcn_mfma_f32_16x16x32_bf16(a1, bw[1][1], aq, 0, 0, 0);
    ar = __builtin_amdgcn_mfma_f32_16x16x32_bf16(a1, bw[2][1], ar, 0, 0, 0);
    #pragma unroll
    for (int r = 0; r < 4; r++) {
      float h = fmaf(ap[r] + bp, sigm_f(aq[r] + bq), tanh_f(ar[r] + br));
      outp[(size_t)(i * 16 + r) * 16] = __float2bfloat16(h);
    }
  }
}

// ---------------------------------------------------------------------------
// K5: per-node batch stats from bf16 h2 -> a[n], c[n]
// ---------------------------------------------------------------------------
__global__ void __launch_bounds__(256) k_stats(
    const __hip_bfloat16* __restrict__ h2b, const float* __restrict__ gamma,
    const float* __restrict__ beta, float* __restrict__ ab) {
  int n = blockIdx.x;
  int tid = threadIdx.x;
  float s = 0.f, s2 = 0.f;
  int part = tid & 1;
  for (int bt2 = tid >> 1; bt2 < 640; bt2 += 128) {
    bf16x8 v = *(const bf16x8*)((const char*)h2b +
        ((size_t)bt2 * 1024 + n) * 32 + part * 16);
    #pragma unroll
    for (int j = 0; j < 8; j++) { float f = bf2f(v[j]); s += f; s2 += f * f; }
  }
  #pragma unroll
  for (int off = 32; off; off >>= 1) { s += __shfl_down(s, off); s2 += __shfl_down(s2, off); }
  __shared__ float rs[4], rs2[4];
  if ((tid & 63) == 0) { rs[tid >> 6] = s; rs2[tid >> 6] = s2; }
  __syncthreads();
  if (tid == 0) {
    float S = rs[0] + rs[1] + rs[2] + rs[3];
    float S2 = rs2[0] + rs2[1] + rs2[2] + rs2[3];
    float mean = S * (1.f / 10240.f);
    float var = S2 * (1.f / 10240.f) - mean * mean;
    float a = gamma[n] * rsqrtf(var + 1e-5f);
    ab[n] = a;
    ab[1024 + n] = beta[n] - mean * a;
  }
}

// ---------------------------------------------------------------------------
// K6: BN + ReLU: bf16 h2 -> f32 d_out
// ---------------------------------------------------------------------------
__global__ void __launch_bounds__(256) k_bnrelu(
    const __hip_bfloat16* __restrict__ h2b, const float* __restrict__ ab,
    float* __restrict__ out) {
  size_t c = (size_t)blockIdx.x * 256 + threadIdx.x;
  int n = (int)((c >> 1) & 1023);
  float a = ab[n], cc = ab[1024 + n];
  bf16x8 v = *(const bf16x8*)((const char*)h2b + c * 16);
  float4* op = reinterpret_cast<float4*>(out + c * 8);
  float4 o0, o1;
  o0.x = fmaxf(0.f, fmaf(bf2f(v[0]), a, cc));
  o0.y = fmaxf(0.f, fmaf(bf2f(v[1]), a, cc));
  o0.z = fmaxf(0.f, fmaf(bf2f(v[2]), a, cc));
  o0.w = fmaxf(0.f, fmaf(bf2f(v[3]), a, cc));
  o1.x = fmaxf(0.f, fmaf(bf2f(v[4]), a, cc));
  o1.y = fmaxf(0.f, fmaf(bf2f(v[5]), a, cc));
  o1.z = fmaxf(0.f, fmaf(bf2f(v[6]), a, cc));
  o1.w = fmaxf(0.f, fmaf(bf2f(v[7]), a, cc));
  op[0] = o0;
  op[1] = o1;
}

// ---------------------------------------------------------------------------
extern "C" void kernel_launch(void* const* d_in, const int* in_sizes, int n_in,
                              void* d_out, int out_size, void* d_ws, size_t ws_size,
                              hipStream_t stream) {
  const float* x     = (const float*)d_in[0];
  const float* cheb  = (const float*)d_in[1];
  const float* t1w1  = (const float*)d_in[2];
  const float* t1b1  = (const float*)d_in[3];
  const float* t1w2  = (const float*)d_in[4];
  const float* t1b2  = (const float*)d_in[5];
  const float* t1w3  = (const float*)d_in[6];
  const float* t1b3  = (const float*)d_in[7];
  const float* wch   = (const float*)d_in[8];
  const float* bch   = (const float*)d_in[9];
  const float* t2w1  = (const float*)d_in[10];
  const float* t2b1  = (const float*)d_in[11];
  const float* t2w2  = (const float*)d_in[12];
  const float* t2b2  = (const float*)d_in[13];
  const float* t2w3  = (const float*)d_in[14];
  const float* t2b3  = (const float*)d_in[15];
  const float* gam   = (const float*)d_in[16];
  const float* bet   = (const float*)d_in[17];

  char* ws = (char*)d_ws;
  __hip_bfloat16* chebT = (__hip_bfloat16*)ws;                   // 6,291,456 B
  __hip_bfloat16* sbuf  = (__hip_bfloat16*)(ws + 6291456);       // 23,068,672 B
  float*          ab    = (float*)(ws + 29360128);               // 8,192 B
  __hip_bfloat16* pbw   = (__hip_bfloat16*)(ws + 29368320);      // 8,192 B (6144 used)
  __hip_bfloat16* h2b   = (__hip_bfloat16*)(ws + 29376512);      // 20,971,520 B
  __hip_bfloat16* hwt   = (__hip_bfloat16*)(ws + 50348032);      // chunk buffer

  size_t avail = ws_size > 50348032 ? ws_size - 50348032 : 0;
  int maxch = (int)(avail / 98304);
  maxch &= ~7;
  if (maxch > 704) maxch = 704;
  if (maxch < 8) maxch = 8;

  k_transpose_cheb<<<769, 256, 0, stream>>>(cheb, chebT, wch, pbw);

  for (int bt0 = 0; bt0 < 704; bt0 += maxch) {
    int ch = (704 - bt0 < maxch) ? (704 - bt0) : maxch;
    k_tcn1_proj<<<ch * 4, 256, 0, stream>>>(x, t1w1, t1b1, t1w2, t1b2, t1w3, t1b3,
                                            pbw, hwt, bt0);
    k_gemm<<<ch, 256, 0, stream>>>(chebT, hwt, bch, sbuf, bt0);
  }

  k_tcn2<<<1280, 256, 0, stream>>>(sbuf, t2w1, t2b1, t2w2, t2b2, t2w3, t2b3, h2b);
  k_stats<<<1024, 256, 0, stream>>>(h2b, gam, bet, ab);
  k_bnrelu<<<5120, 256, 0, stream>>>(h2b, ab, (float*)d_out);
}

// Round 10
// 167.955 us; speedup vs baseline: 1.2289x; 1.0717x over previous
//
#include <hip/hip_runtime.h>
#include <hip/hip_bf16.h>

using bf16x8 = __attribute__((ext_vector_type(8))) short;
using bf16x4 = __attribute__((ext_vector_type(4))) short;
using f32x4  = __attribute__((ext_vector_type(4))) float;
using f32x2  = __attribute__((ext_vector_type(2))) float;

static __device__ __forceinline__ float bf2f(short s) {
  union { unsigned u; float f; } z;
  z.u = ((unsigned)(unsigned short)s) << 16;
  return z.f;
}
static __device__ __forceinline__ short f2bfs(float f) {
  union { __hip_bfloat16 h; short s; } u;
  u.h = __float2bfloat16(f);
  return u.s;
}
static __device__ __forceinline__ float frcp(float x) { return __builtin_amdgcn_rcpf(x); }
static __device__ __forceinline__ float sigm_f(float x) { return frcp(1.f + __expf(-x)); }
static __device__ __forceinline__ float tanh_f(float x) {
  return fmaf(2.f, frcp(1.f + __expf(-2.f * x)), -1.f);
}

typedef const __attribute__((address_space(1))) unsigned int* gas_u32;
typedef __attribute__((address_space(3))) unsigned int* las_u32;
#define GLOAD16(gp, lp) __builtin_amdgcn_global_load_lds( \
    (gas_u32)(const void*)(gp), (las_u32)(void*)(lp), 16, 0, 0)

// ---------------------------------------------------------------------------
// K_front: blockIdx < ch*4  -> fused TCN1 (1->64, gated) + w_cheb proj (MFMA)
//          blockIdx >= ch*4 -> cheb transpose tile (runs only on first chunk)
// Independent outputs (hwt vs chebT); both consumed by k_gemm.
// ---------------------------------------------------------------------------
__global__ void __launch_bounds__(256) k_front(
    const float* __restrict__ x,
    const float* __restrict__ w1, const float* __restrict__ b1,
    const float* __restrict__ w2, const float* __restrict__ b2,
    const float* __restrict__ w3, const float* __restrict__ b3,
    const float* __restrict__ wcheb,
    __hip_bfloat16* __restrict__ hwt, int bt0, int ch,
    const float* __restrict__ cheb, __hip_bfloat16* __restrict__ chebT) {
  __shared__ __align__(16) char smem[32768];
  const int tid = threadIdx.x;

  if ((int)blockIdx.x >= ch * 4) {
    // ---- transpose path: cheb [3][1024][1024] f32 -> chebT bf16 [n][k*1024+m]
    float (*tile)[65] = reinterpret_cast<float (*)[65]>(smem);
    int blk = blockIdx.x - ch * 4;       // 0..767
    int k = blk >> 8;
    int rem = blk & 255;
    int m0 = (rem >> 4) << 6;
    int n0 = (rem & 15) << 6;
    int tx = tid & 63;
    int ty = tid >> 6;
    const float* src = cheb + (size_t)k * 1024 * 1024;
    #pragma unroll
    for (int i = 0; i < 16; i++) {
      int ml = ty + i * 4;
      tile[ml][tx] = src[(size_t)(m0 + ml) * 1024 + n0 + tx];
    }
    __syncthreads();
    #pragma unroll
    for (int i = 0; i < 16; i++) {
      int nl = ty + i * 4;
      chebT[(size_t)(n0 + nl) * 3072 + k * 1024 + m0 + tx] =
          __float2bfloat16(tile[tx][nl]);
    }
    return;
  }

  // ---- TCN1 + projection path
  char* hls = smem;                      // [256 rows][128 B] swizzled
  const int lane = tid & 63, w = tid >> 6;
  const int r16 = lane & 15, kb = lane >> 4;
  const int btl = blockIdx.x >> 2;
  const int m0 = (blockIdx.x & 3) << 8;
  const int bt = bt0 + btl;
  const int b = bt / 22, t = bt % 22;

  const float* xp = x + (size_t)(b * 24 + t) * 1024 + m0 + tid;
  const float x0 = xp[0], x1 = xp[1024], x2 = xp[2048];
  const f32x2 x0v = {x0, x0}, x1v = {x1, x1}, x2v = {x2, x2};

  // B fragments: col o = r16, k-elem c = ks*32 + kb*8 + jj; wcheb[k][c][o]
  bf16x8 bw[3][2];
  #pragma unroll
  for (int kk = 0; kk < 3; kk++)
    #pragma unroll
    for (int ks = 0; ks < 2; ks++)
      #pragma unroll
      for (int jj = 0; jj < 8; jj++)
        bw[kk][ks][jj] = f2bfs(wcheb[kk * 1024 + (ks * 32 + kb * 8 + jj) * 16 + r16]);

  // Phase 1: gated conv (packed f32 pairs), 8 ch/chunk -> swizzled LDS
  const int rswz = (tid & 7) << 4;
  #pragma unroll
  for (int cg = 0; cg < 8; cg++) {
    bf16x8 hv;
    #pragma unroll
    for (int j2 = 0; j2 < 4; j2++) {
      const int c2 = cg * 4 + j2;
      const int wi = 6 * c2;
      f32x2 pw = {b1[2*c2], b1[2*c2+1]};
      f32x2 qw = {b2[2*c2], b2[2*c2+1]};
      f32x2 rw = {b3[2*c2], b3[2*c2+1]};
      pw = __builtin_elementwise_fma(x0v, (f32x2){w1[wi], w1[wi+3]}, pw);
      qw = __builtin_elementwise_fma(x0v, (f32x2){w2[wi], w2[wi+3]}, qw);
      rw = __builtin_elementwise_fma(x0v, (f32x2){w3[wi], w3[wi+3]}, rw);
      pw = __builtin_elementwise_fma(x1v, (f32x2){w1[wi+1], w1[wi+4]}, pw);
      qw = __builtin_elementwise_fma(x1v, (f32x2){w2[wi+1], w2[wi+4]}, qw);
      rw = __builtin_elementwise_fma(x1v, (f32x2){w3[wi+1], w3[wi+4]}, rw);
      pw = __builtin_elementwise_fma(x2v, (f32x2){w1[wi+2], w1[wi+5]}, pw);
      qw = __builtin_elementwise_fma(x2v, (f32x2){w2[wi+2], w2[wi+5]}, qw);
      rw = __builtin_elementwise_fma(x2v, (f32x2){w3[wi+2], w3[wi+5]}, rw);
      hv[j2*2+0] = f2bfs(fmaf(pw.x, sigm_f(qw.x), tanh_f(rw.x)));
      hv[j2*2+1] = f2bfs(fmaf(pw.y, sigm_f(qw.y), tanh_f(rw.y)));
    }
    *(bf16x8*)(hls + tid * 128 + ((cg << 4) ^ rswz)) = hv;
  }
  __syncthreads();

  // Phase 2: projection MFMA. Wave w owns rows [w*64, w*64+64).
  const char* Ab = hls + (w * 64 + r16) * 128;
  const int axor = (r16 & 7) << 4;
  f32x4 acc[4][3];
  #pragma unroll
  for (int mt = 0; mt < 4; mt++)
    #pragma unroll
    for (int kk = 0; kk < 3; kk++) acc[mt][kk] = (f32x4){0.f, 0.f, 0.f, 0.f};

  #pragma unroll
  for (int ks = 0; ks < 2; ks++) {
    #pragma unroll
    for (int mt = 0; mt < 4; mt++) {
      bf16x8 a = *(const bf16x8*)(Ab + mt * 2048 + ((((ks << 2) + kb) << 4) ^ axor));
      #pragma unroll
      for (int kk = 0; kk < 3; kk++)
        acc[mt][kk] = __builtin_amdgcn_mfma_f32_16x16x32_bf16(a, bw[kk][ks], acc[mt][kk], 0, 0, 0);
    }
  }

  __hip_bfloat16* hp = hwt + (size_t)btl * 49152 + r16 * 3072 + m0 + w * 64;
  #pragma unroll
  for (int kk = 0; kk < 3; kk++)
    #pragma unroll
    for (int mt = 0; mt < 4; mt++) {
      bf16x4 v;
      #pragma unroll
      for (int r = 0; r < 4; r++) v[r] = f2bfs(acc[mt][kk][r]);
      *(bf16x4*)(hp + kk * 1024 + mt * 16 + kb * 4) = v;
    }
}

// ---------------------------------------------------------------------------
// K3: tiled GEMM  S[bt][n][o] = ChebT[n][km] * HWT[bt][o][km] + b_cheb[o]
//     EXACT r5 structure (proven 75.5us / 937 TF).
// ---------------------------------------------------------------------------
__global__ void __launch_bounds__(256, 2) k_gemm(
    const __hip_bfloat16* __restrict__ chebT,
    const __hip_bfloat16* __restrict__ hwt,
    const float* __restrict__ b_cheb,
    __hip_bfloat16* __restrict__ sbuf,
    int bt_base) {
  __shared__ __align__(16) char smem[32768];
  const int tid = threadIdx.x;
  const int lane = tid & 63;
  const int w = tid >> 6;

  int nt, ct;
  if (gridDim.x == 704) {
    const int xcd = blockIdx.x & 7;
    const int idx = blockIdx.x >> 3;
    nt = ((xcd >> 2) << 2) + (idx & 3);
    ct = (xcd & 3) * 22 + (idx >> 2);
  } else {
    nt = blockIdx.x & 7;
    ct = blockIdx.x >> 3;
  }

  const int srow = tid >> 3;
  const int sswz = ((tid & 7) ^ (srow & 7)) << 4;
  const char* Ag = (const char*)chebT + (size_t)(nt * 128 + srow) * 6144 + sswz;
  const int btl = srow >> 4, so = srow & 15;
  const char* Bg = (const char*)hwt + (size_t)(ct * 8 + btl) * 98304 + (size_t)so * 6144 + sswz;
  char* Als = smem + w * 1024;
  char* Bls = smem + 16384 + w * 1024;

  const int r16 = lane & 15;
  const int c16 = lane >> 4;
  const int wr = (w >> 1) << 6;
  const int wc = (w & 1) << 6;
  const int axor = (r16 & 7) << 4;
  const char* Abase = smem + (wr + r16) * 128;
  const char* Bbase = smem + 16384 + (wc + r16) * 128;

  f32x4 acc[4][4];
  #pragma unroll
  for (int i = 0; i < 4; i++)
    #pragma unroll
    for (int j = 0; j < 4; j++) acc[i][j] = (f32x4){0.f, 0.f, 0.f, 0.f};

  for (int kt = 0; kt < 48; kt++) {
    __syncthreads();
    const char* a = Ag + kt * 128;
    const char* b = Bg + kt * 128;
    #pragma unroll
    for (int i = 0; i < 4; i++) GLOAD16(a + i * 196608, Als + i * 4096);
    #pragma unroll
    for (int i = 0; i < 4; i++) GLOAD16(b + i * 196608, Bls + i * 4096);
    __syncthreads();
    #pragma unroll
    for (int ksub = 0; ksub < 2; ksub++) {
      const int ko = (ksub * 64 + c16 * 16) ^ axor;
      bf16x8 af[4], bfr[4];
      #pragma unroll
      for (int i = 0; i < 4; i++) af[i] = *(const bf16x8*)(Abase + i * 2048 + ko);
      #pragma unroll
      for (int j = 0; j < 4; j++) bfr[j] = *(const bf16x8*)(Bbase + j * 2048 + ko);
      #pragma unroll
      for (int i = 0; i < 4; i++)
        #pragma unroll
        for (int j = 0; j < 4; j++)
          acc[i][j] = __builtin_amdgcn_mfma_f32_16x16x32_bf16(af[i], bfr[j], acc[i][j], 0, 0, 0);
    }
  }

  float bias = b_cheb[r16];
  #pragma unroll
  for (int j = 0; j < 4; j++) {
    int gcol = ct * 128 + wc + j * 16 + r16;
    size_t bt_g = (size_t)bt_base + (gcol >> 4);
    int o = gcol & 15;
    #pragma unroll
    for (int i = 0; i < 4; i++) {
      int n0 = nt * 128 + wr + i * 16 + c16 * 4;
      __hip_bfloat16* sp = sbuf + (bt_g * 1024 + n0) * 16 + o;
      #pragma unroll
      for (int r = 0; r < 4; r++)
        sp[r * 16] = __float2bfloat16(acc[i][j][r] + bias);
    }
  }
}

// ---------------------------------------------------------------------------
// K4: fused TCN2 (16->16, gated) via MFMA; output bf16 to workspace.
// ---------------------------------------------------------------------------
__global__ void __launch_bounds__(256) k_tcn2(
    const __hip_bfloat16* __restrict__ sbuf,
    const float* __restrict__ w1, const float* __restrict__ b1,
    const float* __restrict__ w2, const float* __restrict__ b2,
    const float* __restrict__ w3, const float* __restrict__ b3,
    __hip_bfloat16* __restrict__ h2b) {
  const int tid = threadIdx.x;
  const int lane = tid & 63, w = tid >> 6;
  const int r16 = lane & 15, kb = lane >> 4;
  const int half = blockIdx.x & 1;
  const int bt2 = blockIdx.x >> 1;
  const int b = bt2 / 20, t2 = bt2 % 20;

  bf16x8 bw[3][2];
  const float* wps[3] = {w1, w2, w3};
  #pragma unroll
  for (int c = 0; c < 3; c++) {
    #pragma unroll
    for (int jj = 0; jj < 8; jj++) {
      int k = kb * 8 + jj;
      bw[c][0][jj] = f2bfs(wps[c][r16 * 48 + (k & 15) * 3 + (k >> 4)]);
      bw[c][1][jj] = (kb < 2) ? f2bfs(wps[c][r16 * 48 + (kb * 8 + jj) * 3 + 2]) : (short)0;
    }
  }
  const float bp = b1[r16], bq = b2[r16], br = b3[r16];

  const char* sb = (const char*)sbuf;
  const size_t slice = (size_t)1024 * 32;
  const int rowbase = half * 512 + w * 128;
  const char* baseA = sb + (size_t)(b * 22 + t2 + (kb >> 1)) * slice
                      + (size_t)(rowbase + r16) * 32 + (kb & 1) * 16;
  const char* baseC = sb + (size_t)(b * 22 + t2 + 2) * slice
                      + (size_t)(rowbase + r16) * 32 + (kb & 1) * 16;
  __hip_bfloat16* outp = h2b + ((size_t)bt2 * 1024 + rowbase + kb * 4) * 16 + r16;

  const f32x4 zro = {0.f, 0.f, 0.f, 0.f};
  #pragma unroll 2
  for (int i = 0; i < 8; i++) {
    bf16x8 a0 = *(const bf16x8*)(baseA + i * 512);
    bf16x8 a1{};
    if (kb < 2) a1 = *(const bf16x8*)(baseC + i * 512);
    f32x4 ap = __builtin_amdgcn_mfma_f32_16x16x32_bf16(a0, bw[0][0], zro, 0, 0, 0);
    f32x4 aq = __builtin_amdgcn_mfma_f32_16x16x32_bf16(a0, bw[1][0], zro, 0, 0, 0);
    f32x4 ar = __builtin_amdgcn_mfma_f32_16x16x32_bf16(a0, bw[2][0], zro, 0, 0, 0);
    ap = __builtin_amdgcn_mfma_f32_16x16x32_bf16(a1, bw[0][1], ap, 0, 0, 0);
    aq = __builtin_amdgcn_mfma_f32_16x16x32_bf16(a1, bw[1][1], aq, 0, 0, 0);
    ar = __builtin_amdgcn_mfma_f32_16x16x32_bf16(a1, bw[2][1], ar, 0, 0, 0);
    #pragma unroll
    for (int r = 0; r < 4; r++) {
      float h = fmaf(ap[r] + bp, sigm_f(aq[r] + bq), tanh_f(ar[r] + br));
      outp[(size_t)(i * 16 + r) * 16] = __float2bfloat16(h);
    }
  }
}

// ---------------------------------------------------------------------------
// K5: fused per-node BN stats + apply + ReLU.  Block = node n.
//     Column (640 rows x 16 ch bf16 = 20480 B) stashed in LDS during the
//     stats read; apply phase reads LDS, writes f32 d_out. One HBM read
//     of h2b total (was two), one kernel boundary removed.
// ---------------------------------------------------------------------------
__global__ void __launch_bounds__(256) k_bnstats(
    const __hip_bfloat16* __restrict__ h2b, const float* __restrict__ gamma,
    const float* __restrict__ beta, float* __restrict__ out) {
  __shared__ __align__(16) short col[10240];     // [640 rows][16 ch]
  __shared__ float rs[4], rs2[4];
  const int n = blockIdx.x;
  const int tid = threadIdx.x;
  const int part = tid & 1;                       // 16B half of the 32B row
  float s = 0.f, s2 = 0.f;
  for (int bt2 = tid >> 1; bt2 < 640; bt2 += 128) {
    bf16x8 v = *(const bf16x8*)((const char*)h2b +
        ((size_t)bt2 * 1024 + n) * 32 + part * 16);
    *(bf16x8*)((char*)col + bt2 * 32 + part * 16) = v;
    #pragma unroll
    for (int j = 0; j < 8; j++) { float f = bf2f(v[j]); s += f; s2 += f * f; }
  }
  #pragma unroll
  for (int off = 32; off; off >>= 1) { s += __shfl_down(s, off); s2 += __shfl_down(s2, off); }
  if ((tid & 63) == 0) { rs[tid >> 6] = s; rs2[tid >> 6] = s2; }
  __syncthreads();
  const float S  = rs[0] + rs[1] + rs[2] + rs[3];
  const float S2 = rs2[0] + rs2[1] + rs2[2] + rs2[3];
  const float mean = S * (1.f / 10240.f);
  const float var  = S2 * (1.f / 10240.f) - mean * mean;
  const float a = gamma[n] * rsqrtf(var + 1e-5f);
  const float c = beta[n] - mean * a;

  for (int bt2 = tid >> 1; bt2 < 640; bt2 += 128) {
    bf16x8 v = *(const bf16x8*)((const char*)col + bt2 * 32 + part * 16);
    float4* op = reinterpret_cast<float4*>(out + ((size_t)bt2 * 1024 + n) * 16 + part * 8);
    float4 o0, o1;
    o0.x = fmaxf(0.f, fmaf(bf2f(v[0]), a, c));
    o0.y = fmaxf(0.f, fmaf(bf2f(v[1]), a, c));
    o0.z = fmaxf(0.f, fmaf(bf2f(v[2]), a, c));
    o0.w = fmaxf(0.f, fmaf(bf2f(v[3]), a, c));
    o1.x = fmaxf(0.f, fmaf(bf2f(v[4]), a, c));
    o1.y = fmaxf(0.f, fmaf(bf2f(v[5]), a, c));
    o1.z = fmaxf(0.f, fmaf(bf2f(v[6]), a, c));
    o1.w = fmaxf(0.f, fmaf(bf2f(v[7]), a, c));
    op[0] = o0;
    op[1] = o1;
  }
}

// ---------------------------------------------------------------------------
extern "C" void kernel_launch(void* const* d_in, const int* in_sizes, int n_in,
                              void* d_out, int out_size, void* d_ws, size_t ws_size,
                              hipStream_t stream) {
  const float* x     = (const float*)d_in[0];
  const float* cheb  = (const float*)d_in[1];
  const float* t1w1  = (const float*)d_in[2];
  const float* t1b1  = (const float*)d_in[3];
  const float* t1w2  = (const float*)d_in[4];
  const float* t1b2  = (const float*)d_in[5];
  const float* t1w3  = (const float*)d_in[6];
  const float* t1b3  = (const float*)d_in[7];
  const float* wch   = (const float*)d_in[8];
  const float* bch   = (const float*)d_in[9];
  const float* t2w1  = (const float*)d_in[10];
  const float* t2b1  = (const float*)d_in[11];
  const float* t2w2  = (const float*)d_in[12];
  const float* t2b2  = (const float*)d_in[13];
  const float* t2w3  = (const float*)d_in[14];
  const float* t2b3  = (const float*)d_in[15];
  const float* gam   = (const float*)d_in[16];
  const float* bet   = (const float*)d_in[17];

  char* ws = (char*)d_ws;
  __hip_bfloat16* chebT = (__hip_bfloat16*)ws;                   // 6,291,456 B
  __hip_bfloat16* sbuf  = (__hip_bfloat16*)(ws + 6291456);       // 23,068,672 B
  __hip_bfloat16* h2b   = (__hip_bfloat16*)(ws + 29360128);      // 20,971,520 B
  __hip_bfloat16* hwt   = (__hip_bfloat16*)(ws + 50331648);      // chunk buffer

  size_t avail = ws_size > 50331648 ? ws_size - 50331648 : 0;
  int maxch = (int)(avail / 98304);
  maxch &= ~7;
  if (maxch > 704) maxch = 704;
  if (maxch < 8) maxch = 8;

  int first = 1;
  for (int bt0 = 0; bt0 < 704; bt0 += maxch) {
    int ch = (704 - bt0 < maxch) ? (704 - bt0) : maxch;
    int extra = first ? 768 : 0;          // transpose tiles ride along once
    k_front<<<ch * 4 + extra, 256, 0, stream>>>(
        x, t1w1, t1b1, t1w2, t1b2, t1w3, t1b3, wch, hwt, bt0, ch, cheb, chebT);
    k_gemm<<<ch, 256, 0, stream>>>(chebT, hwt, bch, sbuf, bt0);
    first = 0;
  }

  k_tcn2<<<1280, 256, 0, stream>>>(sbuf, t2w1, t2b1, t2w2, t2b2, t2w3, t2b3, h2b);
  k_bnstats<<<1024, 256, 0, stream>>>(h2b, gam, bet, (float*)d_out);
}